// Round 1
// baseline (1902.967 us; speedup 1.0000x reference)
//
#include <hip/hip_runtime.h>
#include <hip/hip_bf16.h>
#include <math.h>

#define NN 10000
#define NE 100000
#define NH 8
#define NCH 128
#define NB 32

// ---------------- GEMM: C[M,Nc] = A[M,128] @ W[128,Nc] + bias ----------------
__global__ __launch_bounds__(256) void k_gemm128(
    const float* __restrict__ A, const float* __restrict__ W,
    const float* __restrict__ bias, float* __restrict__ C, int M, int Nc) {
  __shared__ float As[64][128];   // column index XOR-swizzled by row bits
  __shared__ float Ws[128][64];
  const int tid = threadIdx.x;
  const int tx = tid & 15, ty = tid >> 4;
  const int row0 = blockIdx.y * 64, col0 = blockIdx.x * 64;
#pragma unroll
  for (int i = 0; i < 32; ++i) {
    int idx = tid + i * 256;
    int r = idx >> 7, c = idx & 127;
    int gr = row0 + r;
    As[r][c ^ (((r >> 2) & 3) << 3)] = (gr < M) ? A[gr * 128 + c] : 0.f;
  }
#pragma unroll
  for (int i = 0; i < 32; ++i) {
    int idx = tid + i * 256;
    int r = idx >> 6, c = idx & 63;
    Ws[r][c] = W[r * Nc + col0 + c];
  }
  __syncthreads();
  float acc[4][4] = {};
  for (int kk = 0; kk < 128; ++kk) {
    float ra[4], rb[4];
    const int sw = kk ^ ((ty & 3) << 3);
#pragma unroll
    for (int i = 0; i < 4; ++i) ra[i] = As[ty * 4 + i][sw];
#pragma unroll
    for (int j = 0; j < 4; ++j) rb[j] = Ws[kk][tx * 4 + j];
#pragma unroll
    for (int i = 0; i < 4; ++i)
#pragma unroll
      for (int j = 0; j < 4; ++j) acc[i][j] += ra[i] * rb[j];
  }
#pragma unroll
  for (int i = 0; i < 4; ++i) {
    int gr = row0 + ty * 4 + i;
    if (gr >= M) continue;
#pragma unroll
    for (int j = 0; j < 4; ++j) {
      int gc = col0 + tx * 4 + j;
      C[gr * Nc + gc] = acc[i][j] + bias[gc];
    }
  }
}

// ------------- t[n, h*64+d] = sum_c q[n,h*128+c] * We[d*1024 + h*128 + c] -------------
__global__ __launch_bounds__(512) void k_qwe(
    const float* __restrict__ q, const float* __restrict__ We, float* __restrict__ t) {
  const int n = blockIdx.x;
  const int tid = threadIdx.x;
  __shared__ float qs[1024];
  qs[tid] = q[n * 1024 + tid];
  qs[tid + 512] = q[n * 1024 + tid + 512];
  __syncthreads();
  const int h = tid >> 6, d = tid & 63;
  const float* w = We + d * 1024 + h * 128;
  const float* qq = qs + h * 128;
  float s = 0.f;
#pragma unroll 8
  for (int c = 0; c < 128; ++c) s += qq[c] * w[c];
  t[n * 512 + tid] = s;
}

// ---------------- CSR build over dst ----------------
__global__ void k_histo(const int* __restrict__ dst, int* __restrict__ cnt) {
  int e = blockIdx.x * 256 + threadIdx.x;
  if (e < NE) atomicAdd(&cnt[dst[e]], 1);
}

__global__ void k_scan(const int* __restrict__ cnt, int* __restrict__ ptr) {
  __shared__ int buf[256];
  __shared__ int carry;
  const int tid = threadIdx.x;
  if (tid == 0) { carry = 0; ptr[0] = 0; }
  __syncthreads();
  for (int base = 0; base < NN; base += 256) {
    int i = base + tid;
    buf[tid] = (i < NN) ? cnt[i] : 0;
    __syncthreads();
    for (int off = 1; off < 256; off <<= 1) {
      int tv = (tid >= off) ? buf[tid - off] : 0;
      __syncthreads();
      buf[tid] += tv;
      __syncthreads();
    }
    if (i < NN) ptr[i + 1] = carry + buf[tid];
    __syncthreads();
    if (tid == 0) carry += buf[255];
    __syncthreads();
  }
}

__global__ void k_scatter(const int* __restrict__ dst, const int* __restrict__ ptr,
                          int* __restrict__ fill, int* __restrict__ eid) {
  int e = blockIdx.x * 256 + threadIdx.x;
  if (e < NE) {
    int d = dst[e];
    int pos = ptr[d] + atomicAdd(&fill[d], 1);
    eid[pos] = e;
  }
}

// ---------------- per-destination-node attention ----------------
// block = 256 threads = 8 heads x 32 lanes; node n = blockIdx.x
__global__ __launch_bounds__(256) void k_attn(
    const float* __restrict__ q, const float* __restrict__ k, const float* __restrict__ v,
    const float* __restrict__ t, const float* __restrict__ attr, const float* __restrict__ We,
    const int* __restrict__ src, const int* __restrict__ ptr, const int* __restrict__ eid,
    float* __restrict__ exbuf, float* __restrict__ hout) {
  const int n = blockIdx.x;
  const int tid = threadIdx.x;
  const int h = tid >> 5, l = tid & 31;
  __shared__ float qs[1024];
  __shared__ float ts[512];
  __shared__ float s_sh[512];
  for (int i = tid; i < 1024; i += 256) qs[i] = q[n * 1024 + i];
  for (int i = tid; i < 512; i += 256) ts[i] = t[n * 512 + i];
  __syncthreads();
  const int beg = ptr[n], end = ptr[n + 1];
  const float scale = 0.088388347648318447f;  // 1/sqrt(128)

  // pass 1: alpha per (edge, head); store raw alpha; track group max
  float mx = -1e30f;
  for (int idx = beg; idx < end; ++idx) {
    const int e = eid[idx];
    const int sn = src[e];
    const float* kr = k + sn * 1024 + h * 128 + l * 4;
    const float* qr = qs + h * 128 + l * 4;
    float p = qr[0] * kr[0] + qr[1] * kr[1] + qr[2] * kr[2] + qr[3] * kr[3];
    p += ts[h * 64 + l * 2] * attr[e * 64 + l * 2]
       + ts[h * 64 + l * 2 + 1] * attr[e * 64 + l * 2 + 1];
#pragma unroll
    for (int off = 16; off >= 1; off >>= 1) p += __shfl_xor(p, off, 64);
    float alpha = p * scale;
    mx = fmaxf(mx, alpha);
    if (l == 0) exbuf[idx * 8 + h] = alpha;
  }
  __syncthreads();

  // pass 1b: ex = exp(alpha - max); denom
  float den = 0.f;
  for (int idx = beg + l; idx < end; idx += 32) {
    float a = exbuf[idx * 8 + h];
    float ex = __expf(a - mx);
    exbuf[idx * 8 + h] = ex;
    den += ex;
  }
#pragma unroll
  for (int off = 16; off >= 1; off >>= 1) den += __shfl_xor(den, off, 64);
  const float invd = den > 0.f ? 1.f / den : 0.f;
  __syncthreads();

  // pass 2: messages. acc over v[src], plus s[h,d] = sum_e w*attr for the e-part
  float a0 = 0, a1 = 0, a2 = 0, a3 = 0, s0 = 0, s1 = 0;
  for (int idx = beg; idx < end; ++idx) {
    const int e = eid[idx];
    const int sn = src[e];
    const float w = exbuf[idx * 8 + h] * invd;
    const float* vr = v + sn * 1024 + h * 128 + l * 4;
    a0 += w * vr[0]; a1 += w * vr[1]; a2 += w * vr[2]; a3 += w * vr[3];
    s0 += w * attr[e * 64 + l * 2];
    s1 += w * attr[e * 64 + l * 2 + 1];
  }
  s_sh[h * 64 + l * 2] = s0;
  s_sh[h * 64 + l * 2 + 1] = s1;
  __syncthreads();

  // e-part of message: acc[c] += sum_d s[h,d] * We[d, h*128+c]
  const float* wb = We + h * 128 + l * 4;
  for (int d = 0; d < 64; ++d) {
    const float sv = s_sh[h * 64 + d];
    const float* wr = wb + d * 1024;
    a0 += sv * wr[0]; a1 += sv * wr[1]; a2 += sv * wr[2]; a3 += sv * wr[3];
  }
  __syncthreads();
  qs[h * 128 + l * 4 + 0] = a0;
  qs[h * 128 + l * 4 + 1] = a1;
  qs[h * 128 + l * 4 + 2] = a2;
  qs[h * 128 + l * 4 + 3] = a3;
  __syncthreads();

  // head mean + skip (hout pre-filled with x @ Wskip + bskip)
  if (tid < 128) {
    float sum = 0.f;
#pragma unroll
    for (int hh = 0; hh < 8; ++hh) sum += qs[hh * 128 + tid];
    hout[n * 128 + tid] += sum * 0.125f;
  }
}

// ---------------- GraphNorm + LeakyReLU ----------------
__global__ void k_gn_sum(const float* __restrict__ x, const int* __restrict__ batch,
                         float* __restrict__ sum, int* __restrict__ cnt) {
  int i = blockIdx.x * 256 + threadIdx.x;
  if (i < NN * 128) {
    int n = i >> 7, c = i & 127;
    int b = batch[n];
    atomicAdd(&sum[b * 128 + c], x[i]);
    if (c == 0) atomicAdd(&cnt[b], 1);
  }
}

__global__ void k_gn_center(float* __restrict__ x, const int* __restrict__ batch,
                            const float* __restrict__ sum, const int* __restrict__ cnt,
                            const float* __restrict__ ms, float* __restrict__ var) {
  int i = blockIdx.x * 256 + threadIdx.x;
  if (i < NN * 128) {
    int n = i >> 7, c = i & 127;
    int b = batch[n];
    float fc = fmaxf((float)cnt[b], 1.f);
    float o = x[i] - (sum[b * 128 + c] / fc) * ms[c];
    x[i] = o;
    atomicAdd(&var[b * 128 + c], o * o);
  }
}

__global__ void k_gn_final(const float* __restrict__ x, const int* __restrict__ batch,
                           const float* __restrict__ var, const int* __restrict__ cnt,
                           const float* __restrict__ w, const float* __restrict__ bb,
                           float* __restrict__ out) {
  int i = blockIdx.x * 256 + threadIdx.x;
  if (i < NN * 128) {
    int n = i >> 7, c = i & 127;
    int b = batch[n];
    float fc = fmaxf((float)cnt[b], 1.f);
    float o = x[i] * rsqrtf(var[b * 128 + c] / fc + 1e-5f) * w[c] + bb[c];
    out[i] = o > 0.f ? o : 0.01f * o;
  }
}

extern "C" void kernel_launch(void* const* d_in, const int* in_sizes, int n_in,
                              void* d_out, int out_size, void* d_ws, size_t ws_size,
                              hipStream_t stream) {
  const float* x     = (const float*)d_in[0];
  const int*   index = (const int*)d_in[1];
  const float* attr  = (const float*)d_in[2];
  const int*   batch = (const int*)d_in[3];
  const int* srcArr = index;        // index[0]
  const int* dstArr = index + NE;   // index[1]

  char* p = (char*)d_ws;
  auto take = [&](size_t bytes) {
    char* r = p;
    p += (bytes + 255) & ~(size_t)255;
    return (void*)r;
  };
  float* q     = (float*)take((size_t)NN * 1024 * 4);
  float* kbuf  = (float*)take((size_t)NN * 1024 * 4);
  float* vbuf  = (float*)take((size_t)NN * 1024 * 4);
  float* tbuf  = (float*)take((size_t)NN * 512 * 4);
  float* hbuf  = (float*)take((size_t)NN * 128 * 4);
  float* x2    = (float*)take((size_t)NN * 128 * 4);
  float* exbuf = (float*)take((size_t)NE * 8 * 4);
  float* gnsum = (float*)take((size_t)NB * 128 * 4);   // gnsum/gnvar/gncnt contiguous
  float* gnvar = (float*)take((size_t)NB * 128 * 4);
  int*   gncnt = (int*)take((size_t)NB * 4);
  int* csr_ptr = (int*)take((size_t)(NN + 1) * 4);
  int* csr_cnt = (int*)take((size_t)NN * 4);
  int* csr_eid = (int*)take((size_t)NE * 4);

  // ---- CSR build over dst (same for both layers) ----
  hipMemsetAsync(csr_cnt, 0, NN * 4, stream);
  k_histo<<<(NE + 255) / 256, 256, 0, stream>>>(dstArr, csr_cnt);
  k_scan<<<1, 256, 0, stream>>>(csr_cnt, csr_ptr);
  hipMemsetAsync(csr_cnt, 0, NN * 4, stream);
  k_scatter<<<(NE + 255) / 256, 256, 0, stream>>>(dstArr, csr_ptr, csr_cnt, csr_eid);

  for (int L = 0; L < 2; ++L) {
    const float* Wq  = (const float*)d_in[4 + L * 12 + 0];
    const float* bq  = (const float*)d_in[4 + L * 12 + 1];
    const float* Wk  = (const float*)d_in[4 + L * 12 + 2];
    const float* bk  = (const float*)d_in[4 + L * 12 + 3];
    const float* Wv  = (const float*)d_in[4 + L * 12 + 4];
    const float* bv  = (const float*)d_in[4 + L * 12 + 5];
    const float* We  = (const float*)d_in[4 + L * 12 + 6];
    const float* Wsk = (const float*)d_in[4 + L * 12 + 7];
    const float* bsk = (const float*)d_in[4 + L * 12 + 8];
    const float* gnw = (const float*)d_in[4 + L * 12 + 9];
    const float* gnb = (const float*)d_in[4 + L * 12 + 10];
    const float* gnm = (const float*)d_in[4 + L * 12 + 11];
    const float* xin = (L == 0) ? x : x2;
    float* xout = (L == 0) ? x2 : (float*)d_out;

    dim3 gqkv(1024 / 64, (NN + 63) / 64);
    k_gemm128<<<gqkv, 256, 0, stream>>>(xin, Wq, bq, q, NN, 1024);
    k_gemm128<<<gqkv, 256, 0, stream>>>(xin, Wk, bk, kbuf, NN, 1024);
    k_gemm128<<<gqkv, 256, 0, stream>>>(xin, Wv, bv, vbuf, NN, 1024);
    dim3 gskip(128 / 64, (NN + 63) / 64);
    k_gemm128<<<gskip, 256, 0, stream>>>(xin, Wsk, bsk, hbuf, NN, 128);
    k_qwe<<<NN, 512, 0, stream>>>(q, We, tbuf);
    k_attn<<<NN, 256, 0, stream>>>(q, kbuf, vbuf, tbuf, attr, We,
                                   srcArr, csr_ptr, csr_eid, exbuf, hbuf);
    hipMemsetAsync(gnsum, 0, (size_t)(NB * 128 * 2 + NB) * 4, stream);
    int gn_blocks = (NN * 128 + 255) / 256;
    k_gn_sum<<<gn_blocks, 256, 0, stream>>>(hbuf, batch, gnsum, gncnt);
    k_gn_center<<<gn_blocks, 256, 0, stream>>>(hbuf, batch, gnsum, gncnt, gnm, gnvar);
    k_gn_final<<<gn_blocks, 256, 0, stream>>>(hbuf, batch, gnvar, gncnt, gnw, gnb, xout);
  }
}

// Round 2
// 761.130 us; speedup vs baseline: 2.5002x; 2.5002x over previous
//
#include <hip/hip_runtime.h>
#include <hip/hip_bf16.h>
#include <math.h>

#define NN 10000
#define NE 100000
#define NB 32

typedef __attribute__((ext_vector_type(8))) short short8;
typedef __attribute__((ext_vector_type(4))) float f32x4;

__device__ inline ushort f2b(float f) {
  union { float f; unsigned u; } a; a.f = f;
  unsigned r = a.u + 0x7fff + ((a.u >> 16) & 1);
  return (ushort)(r >> 16);
}

// ---------------- bf16 MFMA GEMM: C[M,Nc] = A[M,128] @ W[128,Nc] + bias -------
// Abf: [M][128] bf16 row-major. Bt: [Nc][128] bf16 (W transposed). ldc = Nc.
__global__ __launch_bounds__(256) void k_mfma_gemm(
    const ushort* __restrict__ Abf, const ushort* __restrict__ Bt,
    const float* __restrict__ bias, float* __restrict__ C, int M, int ldc) {
  __shared__ ushort As[128 * 128];
  __shared__ ushort Bs[128 * 128];
  const int tid = threadIdx.x;
  const int l = tid & 63, w = tid >> 6;
  const int wm = w & 1, wn = w >> 1;
  const int row0 = blockIdx.y * 128, col0 = blockIdx.x * 128;
#pragma unroll
  for (int i = 0; i < 8; ++i) {
    int idx = i * 256 + tid;            // 16B-unit index, 2048 total
    int r = idx >> 4, cb = (idx & 15) << 4;
    int swz = cb ^ ((r & 7) << 4);
    int gr = row0 + r;
    ulonglong2 va = {0ull, 0ull};
    if (gr < M) va = *(const ulonglong2*)((const char*)Abf + (size_t)gr * 256 + cb);
    *(ulonglong2*)((char*)As + r * 256 + swz) = va;
    ulonglong2 vb = *(const ulonglong2*)((const char*)Bt + (size_t)(col0 + r) * 256 + cb);
    *(ulonglong2*)((char*)Bs + r * 256 + swz) = vb;
  }
  __syncthreads();
  f32x4 acc[4][4] = {};
#pragma unroll
  for (int kk = 0; kk < 4; ++kk) {
    short8 af[4], bf[4];
#pragma unroll
    for (int fm = 0; fm < 4; ++fm) {
      int r = wm * 64 + fm * 16 + (l & 15);
      int cb = (kk * 64 + ((l >> 4) << 4)) ^ ((r & 7) << 4);
      af[fm] = *(const short8*)((const char*)As + r * 256 + cb);
    }
#pragma unroll
    for (int fn = 0; fn < 4; ++fn) {
      int r = wn * 64 + fn * 16 + (l & 15);
      int cb = (kk * 64 + ((l >> 4) << 4)) ^ ((r & 7) << 4);
      bf[fn] = *(const short8*)((const char*)Bs + r * 256 + cb);
    }
#pragma unroll
    for (int fm = 0; fm < 4; ++fm)
#pragma unroll
      for (int fn = 0; fn < 4; ++fn)
        acc[fm][fn] = __builtin_amdgcn_mfma_f32_16x16x32_bf16(af[fm], bf[fn], acc[fm][fn], 0, 0, 0);
  }
#pragma unroll
  for (int fm = 0; fm < 4; ++fm) {
    int row = row0 + wm * 64 + fm * 16 + ((l >> 4) << 2);
#pragma unroll
    for (int fn = 0; fn < 4; ++fn) {
      int col = col0 + wn * 64 + fn * 16 + (l & 15);
      float bb = bias[col];
#pragma unroll
      for (int b = 0; b < 4; ++b)
        if (row + b < M) C[(size_t)(row + b) * ldc + col] = acc[fm][fn][b] + bb;
    }
  }
}

// ---------------- weight prep ----------------
// Wt[nc][kc] = bf16(W[kc*Nc + nc]); grid (Nc/32, 4), 256 thr
__global__ void k_wt(const float* __restrict__ W, ushort* __restrict__ Wt, int Nc) {
  __shared__ float tile[32][33];
  const int t = threadIdx.x, lx = t & 31, ly = t >> 5;
  const int bx = blockIdx.x, by = blockIdx.y;
#pragma unroll
  for (int i = 0; i < 4; ++i)
    tile[ly + i * 8][lx] = W[(by * 32 + ly + i * 8) * Nc + bx * 32 + lx];
  __syncthreads();
#pragma unroll
  for (int i = 0; i < 4; ++i)
    Wt[(size_t)(bx * 32 + ly + i * 8) * 128 + by * 32 + lx] = f2b(tile[lx][ly + i * 8]);
}

// Mt[(h*64+d)*128 + p] = bf16( sum_c Wq[p,h*128+c] * We[d,h*128+c] ); grid 64
__global__ __launch_bounds__(256) void k_mwt(
    const float* __restrict__ Wq, const float* __restrict__ We, ushort* __restrict__ Mt) {
  const int h = blockIdx.x >> 3, pt = blockIdx.x & 7;
  const int t = threadIdx.x;
  __shared__ float Wes[64][129];
  __shared__ float Wqs[16][129];
#pragma unroll
  for (int i = 0; i < 32; ++i) {
    int idx = i * 256 + t;
    Wes[idx >> 7][idx & 127] = We[(idx >> 7) * 1024 + h * 128 + (idx & 127)];
  }
#pragma unroll
  for (int i = 0; i < 8; ++i) {
    int idx = i * 256 + t;
    Wqs[idx >> 7][idx & 127] = Wq[(pt * 16 + (idx >> 7)) * 1024 + h * 128 + (idx & 127)];
  }
  __syncthreads();
#pragma unroll
  for (int i = 0; i < 4; ++i) {
    int o = i * 256 + t;
    int d = o & 63, p = o >> 6;
    float s = 0.f;
#pragma unroll 8
    for (int c = 0; c < 128; ++c) s += Wqs[p][c] * Wes[d][c];
    Mt[(size_t)(h * 64 + d) * 128 + pt * 16 + p] = f2b(s);
  }
}

__global__ void k_tbias(const float* __restrict__ bq, const float* __restrict__ We,
                        float* __restrict__ tb) {
  int o = blockIdx.x * 256 + threadIdx.x;
  if (o < 512) {
    int h = o >> 6, d = o & 63;
    float s = 0.f;
    for (int c = 0; c < 128; ++c) s += bq[h * 128 + c] * We[d * 1024 + h * 128 + c];
    tb[o] = s;
  }
}

__global__ void k_bias_cat(const float* __restrict__ a, const float* __restrict__ b,
                           const float* __restrict__ c, float* __restrict__ out) {
  int i = blockIdx.x * 256 + threadIdx.x;
  if (i < 1024) out[i] = a[i];
  else if (i < 2048) out[i] = b[i - 1024];
  else if (i < 3072) out[i] = c[i - 2048];
}

__global__ void k_cvt(const float* __restrict__ in, ushort* __restrict__ out) {
  int i = (blockIdx.x * 256 + threadIdx.x) * 4;
  float4 v = *(const float4*)(in + i);
  ushort4 o;
  o.x = f2b(v.x); o.y = f2b(v.y); o.z = f2b(v.z); o.w = f2b(v.w);
  *(ushort4*)(out + i) = o;
}

// ---------------- CSR build over dst ----------------
__global__ void k_histo(const int* __restrict__ dst, int* __restrict__ cnt) {
  int e = blockIdx.x * 256 + threadIdx.x;
  if (e < NE) atomicAdd(&cnt[dst[e]], 1);
}

__global__ void k_scan(const int* __restrict__ cnt, int* __restrict__ ptr) {
  __shared__ int buf[256];
  __shared__ int carry;
  const int tid = threadIdx.x;
  if (tid == 0) { carry = 0; ptr[0] = 0; }
  __syncthreads();
  for (int base = 0; base < NN; base += 256) {
    int i = base + tid;
    buf[tid] = (i < NN) ? cnt[i] : 0;
    __syncthreads();
    for (int off = 1; off < 256; off <<= 1) {
      int tv = (tid >= off) ? buf[tid - off] : 0;
      __syncthreads();
      buf[tid] += tv;
      __syncthreads();
    }
    if (i < NN) ptr[i + 1] = carry + buf[tid];
    __syncthreads();
    if (tid == 0) carry += buf[255];
    __syncthreads();
  }
}

__global__ void k_scatter(const int* __restrict__ dst, const int* __restrict__ ptr,
                          int* __restrict__ fill, int* __restrict__ eid) {
  int e = blockIdx.x * 256 + threadIdx.x;
  if (e < NE) {
    int d = dst[e];
    int pos = ptr[d] + atomicAdd(&fill[d], 1);
    eid[pos] = e;
  }
}

// ---------------- batch boundaries ----------------
__global__ void k_bhisto(const int* __restrict__ batch, int* __restrict__ cnt) {
  int n = blockIdx.x * 256 + threadIdx.x;
  if (n < NN) atomicAdd(&cnt[batch[n]], 1);
}

__global__ void k_bscan(const int* __restrict__ cnt, int* __restrict__ ptr) {
  if (threadIdx.x == 0) {
    int s = 0;
    ptr[0] = 0;
    for (int b = 0; b < NB; ++b) { s += cnt[b]; ptr[b + 1] = s; }
  }
}

// ---------------- per-destination-node attention ----------------
// qkv row stride 3072: q = +0, k = +1024, v = +2048
__global__ __launch_bounds__(256) void k_attn(
    const float* __restrict__ qkv, const float* __restrict__ t,
    const float* __restrict__ attr, const float* __restrict__ We,
    const int* __restrict__ src, const int* __restrict__ ptr, const int* __restrict__ eid,
    float* __restrict__ exbuf, float* __restrict__ hout) {
  const int n = blockIdx.x;
  const int tid = threadIdx.x;
  const int h = tid >> 5, l = tid & 31;
  __shared__ float qs[1024];
  __shared__ float ts[512];
  __shared__ float s_sh[512];
  for (int i = tid; i < 1024; i += 256) qs[i] = qkv[(size_t)n * 3072 + i];
  for (int i = tid; i < 512; i += 256) ts[i] = t[n * 512 + i];
  __syncthreads();
  const int beg = ptr[n], end = ptr[n + 1];
  const float scale = 0.088388347648318447f;  // 1/sqrt(128)

  float mx = -1e30f;
  for (int idx = beg; idx < end; ++idx) {
    const int e = eid[idx];
    const int sn = src[e];
    const float* kr = qkv + (size_t)sn * 3072 + 1024 + h * 128 + l * 4;
    const float* qr = qs + h * 128 + l * 4;
    float p = qr[0] * kr[0] + qr[1] * kr[1] + qr[2] * kr[2] + qr[3] * kr[3];
    p += ts[h * 64 + l * 2] * attr[e * 64 + l * 2]
       + ts[h * 64 + l * 2 + 1] * attr[e * 64 + l * 2 + 1];
#pragma unroll
    for (int off = 16; off >= 1; off >>= 1) p += __shfl_xor(p, off, 64);
    float alpha = p * scale;
    mx = fmaxf(mx, alpha);
    if (l == 0) exbuf[idx * 8 + h] = alpha;
  }
  __syncthreads();

  float den = 0.f;
  for (int idx = beg + l; idx < end; idx += 32) {
    float a = exbuf[idx * 8 + h];
    float ex = __expf(a - mx);
    exbuf[idx * 8 + h] = ex;
    den += ex;
  }
#pragma unroll
  for (int off = 16; off >= 1; off >>= 1) den += __shfl_xor(den, off, 64);
  const float invd = den > 0.f ? 1.f / den : 0.f;
  __syncthreads();

  float a0 = 0, a1 = 0, a2 = 0, a3 = 0, s0 = 0, s1 = 0;
  for (int idx = beg; idx < end; ++idx) {
    const int e = eid[idx];
    const int sn = src[e];
    const float w = exbuf[idx * 8 + h] * invd;
    const float* vr = qkv + (size_t)sn * 3072 + 2048 + h * 128 + l * 4;
    a0 += w * vr[0]; a1 += w * vr[1]; a2 += w * vr[2]; a3 += w * vr[3];
    s0 += w * attr[e * 64 + l * 2];
    s1 += w * attr[e * 64 + l * 2 + 1];
  }
  s_sh[h * 64 + l * 2] = s0;
  s_sh[h * 64 + l * 2 + 1] = s1;
  __syncthreads();

  const float* wb = We + h * 128 + l * 4;
  for (int d = 0; d < 64; ++d) {
    const float sv = s_sh[h * 64 + d];
    const float* wr = wb + d * 1024;
    a0 += sv * wr[0]; a1 += sv * wr[1]; a2 += sv * wr[2]; a3 += sv * wr[3];
  }
  __syncthreads();
  qs[h * 128 + l * 4 + 0] = a0;
  qs[h * 128 + l * 4 + 1] = a1;
  qs[h * 128 + l * 4 + 2] = a2;
  qs[h * 128 + l * 4 + 3] = a3;
  __syncthreads();

  if (tid < 128) {
    float sum = 0.f;
#pragma unroll
    for (int hh = 0; hh < 8; ++hh) sum += qs[hh * 128 + tid];
    hout[n * 128 + tid] += sum * 0.125f;
  }
}

// ---------------- GraphNorm (atomic-free) ----------------
__global__ __launch_bounds__(256) void k_gn_stats(
    const float* __restrict__ x, const int* __restrict__ bptr,
    const float* __restrict__ ms, const float* __restrict__ w,
    float2* __restrict__ stat) {
  const int b = blockIdx.x;
  const int t = threadIdx.x;
  const int c = t & 127, half = t >> 7;
  const int beg = bptr[b], end = bptr[b + 1];
  float s = 0.f, s2 = 0.f;
  for (int n = beg + half; n < end; n += 2) {
    float v = x[(size_t)n * 128 + c];
    s += v; s2 += v * v;
  }
  __shared__ float r1[256];
  __shared__ float r2[256];
  r1[t] = s; r2[t] = s2;
  __syncthreads();
  if (half == 0) {
    float S = r1[c] + r1[c + 128];
    float S2 = r2[c] + r2[c + 128];
    float fc = fmaxf((float)(end - beg), 1.f);
    float mean = S / fc;
    float mm = mean * ms[c];
    float var = S2 / fc - 2.f * mm * mean + mm * mm;
    stat[b * 128 + c] = make_float2(mm, rsqrtf(var + 1e-5f) * w[c]);
  }
}

__global__ void k_gn_apply(const float* __restrict__ x, const int* __restrict__ batch,
                           const float2* __restrict__ stat, const float* __restrict__ gnb,
                           float* __restrict__ fout, ushort* __restrict__ bout) {
  int i = blockIdx.x * 256 + threadIdx.x;
  int n = i >> 7, c = i & 127;
  int b = batch[n];
  float2 st = stat[b * 128 + c];
  float o = (x[i] - st.x) * st.y + gnb[c];
  o = o > 0.f ? o : 0.01f * o;
  if (fout) fout[i] = o;
  if (bout) bout[i] = f2b(o);
}

extern "C" void kernel_launch(void* const* d_in, const int* in_sizes, int n_in,
                              void* d_out, int out_size, void* d_ws, size_t ws_size,
                              hipStream_t stream) {
  const float* x     = (const float*)d_in[0];
  const int*   index = (const int*)d_in[1];
  const float* attr  = (const float*)d_in[2];
  const int*   batch = (const int*)d_in[3];
  const int* srcArr = index;
  const int* dstArr = index + NE;

  char* p = (char*)d_ws;
  auto take = [&](size_t bytes) {
    char* r = p;
    p += (bytes + 255) & ~(size_t)255;
    return (void*)r;
  };
  float*  qkv   = (float*)take((size_t)NN * 3072 * 4);
  float*  tbuf  = (float*)take((size_t)NN * 512 * 4);
  float*  hbuf  = (float*)take((size_t)NN * 128 * 4);
  ushort* xb    = (ushort*)take((size_t)NN * 128 * 2);
  ushort* x2b   = (ushort*)take((size_t)NN * 128 * 2);
  float*  exbuf = (float*)take((size_t)NE * 8 * 4);
  float2* stat  = (float2*)take((size_t)NB * 128 * 8);
  int* csr_ptr  = (int*)take((size_t)(NN + 1) * 4);
  int* csr_cnt  = (int*)take((size_t)NN * 4);
  int* csr_eid  = (int*)take((size_t)NE * 4);
  int* bcnt     = (int*)take((size_t)NB * 4);
  int* bptrd    = (int*)take((size_t)(NB + 1) * 4);
  ushort* WtQKV[2]; ushort* Wtsk[2]; ushort* Mt[2];
  float* bias3[2]; float* tbias[2];
  for (int L = 0; L < 2; ++L) {
    WtQKV[L] = (ushort*)take((size_t)3072 * 128 * 2);
    Wtsk[L]  = (ushort*)take((size_t)128 * 128 * 2);
    Mt[L]    = (ushort*)take((size_t)512 * 128 * 2);
    bias3[L] = (float*)take((size_t)3072 * 4);
    tbias[L] = (float*)take((size_t)512 * 4);
  }

  // ---- CSR over dst + batch boundaries (input-dependent only) ----
  hipMemsetAsync(csr_cnt, 0, NN * 4, stream);
  k_histo<<<(NE + 255) / 256, 256, 0, stream>>>(dstArr, csr_cnt);
  k_scan<<<1, 256, 0, stream>>>(csr_cnt, csr_ptr);
  hipMemsetAsync(csr_cnt, 0, NN * 4, stream);
  k_scatter<<<(NE + 255) / 256, 256, 0, stream>>>(dstArr, csr_ptr, csr_cnt, csr_eid);
  hipMemsetAsync(bcnt, 0, NB * 4, stream);
  k_bhisto<<<(NN + 255) / 256, 256, 0, stream>>>(batch, bcnt);
  k_bscan<<<1, 64, 0, stream>>>(bcnt, bptrd);
  k_cvt<<<NN * 128 / 1024, 256, 0, stream>>>(x, xb);

  // ---- weight prep (both layers) ----
  for (int L = 0; L < 2; ++L) {
    const float* Wq  = (const float*)d_in[4 + L * 12 + 0];
    const float* bq  = (const float*)d_in[4 + L * 12 + 1];
    const float* Wk  = (const float*)d_in[4 + L * 12 + 2];
    const float* bk  = (const float*)d_in[4 + L * 12 + 3];
    const float* Wv  = (const float*)d_in[4 + L * 12 + 4];
    const float* bv  = (const float*)d_in[4 + L * 12 + 5];
    const float* We  = (const float*)d_in[4 + L * 12 + 6];
    const float* Wsk = (const float*)d_in[4 + L * 12 + 7];
    k_wt<<<dim3(32, 4), 256, 0, stream>>>(Wq, WtQKV[L], 1024);
    k_wt<<<dim3(32, 4), 256, 0, stream>>>(Wk, WtQKV[L] + 1024 * 128, 1024);
    k_wt<<<dim3(32, 4), 256, 0, stream>>>(Wv, WtQKV[L] + 2048 * 128, 1024);
    k_wt<<<dim3(4, 4), 256, 0, stream>>>(Wsk, Wtsk[L], 128);
    k_mwt<<<64, 256, 0, stream>>>(Wq, We, Mt[L]);
    k_tbias<<<2, 256, 0, stream>>>(bq, We, tbias[L]);
    k_bias_cat<<<12, 256, 0, stream>>>(bq, bk, bv, bias3[L]);
  }

  const int MT = (NN + 127) / 128;  // 79 row tiles
  for (int L = 0; L < 2; ++L) {
    const float* We   = (const float*)d_in[4 + L * 12 + 6];
    const float* bsk  = (const float*)d_in[4 + L * 12 + 8];
    const float* gnw  = (const float*)d_in[4 + L * 12 + 9];
    const float* gnb  = (const float*)d_in[4 + L * 12 + 10];
    const float* gnm  = (const float*)d_in[4 + L * 12 + 11];
    const ushort* Ain = (L == 0) ? xb : x2b;

    k_mfma_gemm<<<dim3(24, MT), 256, 0, stream>>>(Ain, WtQKV[L], bias3[L], qkv, NN, 3072);
    k_mfma_gemm<<<dim3(1, MT), 256, 0, stream>>>(Ain, Wtsk[L], bsk, hbuf, NN, 128);
    k_mfma_gemm<<<dim3(4, MT), 256, 0, stream>>>(Ain, Mt[L], tbias[L], tbuf, NN, 512);
    k_attn<<<NN, 256, 0, stream>>>(qkv, tbuf, attr, We, srcArr, csr_ptr, csr_eid, exbuf, hbuf);
    k_gn_stats<<<NB, 256, 0, stream>>>(hbuf, bptrd, gnm, gnw, stat);
    k_gn_apply<<<NN * 128 / 256, 256, 0, stream>>>(
        hbuf, batch, stat, gnb,
        (L == 0) ? (float*)nullptr : (float*)d_out,
        (L == 0) ? x2b : (ushort*)nullptr);
  }
}